// Round 5
// baseline (1585.571 us; speedup 1.0000x reference)
//
#include <hip/hip_runtime.h>

typedef __bf16 v8bf __attribute__((ext_vector_type(8)));
typedef float v4f __attribute__((ext_vector_type(4)));
typedef unsigned short u16;
typedef unsigned int u32;

#define DEVI __device__ __forceinline__
#define SGB(m, n) __builtin_amdgcn_sched_group_barrier((m), (n), 0)
// masks: VALU=0x2 MFMA=0x8 VMEM_READ=0x20 DS_READ=0x100

constexpr int LX = 168, FF = 64;
constexpr int LY = 72, FT = 22, FOUTC = 10;
constexpr int HID = 256;
constexpr int HSTR = 264;   // u16/row for 16x256 tiles (528B = 33*16)
constexpr int UST2 = 40;
constexpr int SSTR = 264;   // slab row stride
constexpr int XSTR = 72;    // encoder x-stage row stride (u16)

// bf16 weight cache layout in d_ws (u16 element offsets; all 16B-aligned)
constexpr int W_EWIH = 0;                      // 768*64
constexpr int W_EWHH = 49152;                  // 768*256
constexpr int W_DWIH = 245760;                 // 768*32
constexpr int W_DWHH = 270336;                 // 768*256
constexpr int W_THW0 = 466944;                 // 128*256
constexpr int W_THW1 = 499712;                 // 2*128
constexpr int W_CLW0 = 499968;                 // 128*256
constexpr int W_CLW1 = 532736;                 // 8*128
constexpr int W_W1F  = 533760;                 // fused padded W1: 16 x 256
constexpr int W_TOTALF = 537856;               // incl. W1F

DEVI u16 f2bf(float f) {
  u32 x; __builtin_memcpy(&x, &f, 4);
  return (u16)((x + 0x7FFFu + ((x >> 16) & 1u)) >> 16);  // RNE (h feeds recurrence)
}
DEVI float sigm(float x) { return __builtin_amdgcn_rcpf(1.f + __expf(-x)); }
DEVI float tanh_(float x) {
  float e = __expf(-2.f * fabsf(x));
  return copysignf((1.f - e) * __builtin_amdgcn_rcpf(1.f + e), x);
}
DEVI float smelu_(float x) {
  if (x >= 1.1f) return x;
  if (x <= -1.1f) return 0.f;
  float u = x + 1.1f;
  return u * u * (1.f / 4.4f);
}
DEVI v8bf ld8(const u16* p) { return *reinterpret_cast<const v8bf*>(p); }
DEVI v4f ldw(const u16* p) { return *reinterpret_cast<const v4f*>(p); }
DEVI v8bf asbf(v4f x) { return __builtin_bit_cast(v8bf, x); }
DEVI void pina(v4f& x) { asm("" : "+a"(x)); }      // park in AGPR (not arch VGPR!)
DEVI v4f mfma16(v8bf a, v8bf b, v4f c) {
  return __builtin_amdgcn_mfma_f32_16x16x32_bf16(a, b, c, 0, 0, 0);
}

// ---- prologue: convert all weight matrices f32 -> bf16 into d_ws ----
// Also builds W1F: fused padded head-W1, 16 out-cols x 256 K where
// K 0..127 = temphr activations, 128..255 = class activations.
__global__ void cvt_weights(const float* __restrict__ eWih, const float* __restrict__ eWhh,
                            const float* __restrict__ dWih, const float* __restrict__ dWhh,
                            const float* __restrict__ thW0, const float* __restrict__ thW1,
                            const float* __restrict__ clW0, const float* __restrict__ clW1,
                            u16* __restrict__ ws) {
  const int i = blockIdx.x * 256 + threadIdx.x;
  if (i >= W_TOTALF) return;
  if (i >= W_W1F) {
    const int r = i - W_W1F, c = r >> 8, k = r & 255;
    float v = 0.f;
    if (c < 2 && k < 128) v = thW1[c * 128 + k];
    else if (c >= 2 && c < FOUTC && k >= 128) v = clW1[(c - 2) * 128 + (k - 128)];
    ws[i] = f2bf(v);
    return;
  }
  const float* src; int off;
  if      (i < W_EWHH) { src = eWih; off = W_EWIH; }
  else if (i < W_DWIH) { src = eWhh; off = W_EWHH; }
  else if (i < W_DWHH) { src = dWih; off = W_DWIH; }
  else if (i < W_THW0) { src = dWhh; off = W_DWHH; }
  else if (i < W_THW1) { src = thW0; off = W_THW0; }
  else if (i < W_CLW0) { src = thW1; off = W_THW1; }
  else if (i < W_CLW1) { src = clW0; off = W_CLW0; }
  else                 { src = clW1; off = W_CLW1; }
  ws[i] = f2bf(src[i - off]);
}

// 1024 threads = 16 waves @ 4 waves/SIMD. Wave w owns ONE col-tile c = w.
// 128 regs/wave = 64 AGPR (z,n Whh, pinned via "+a") + 64 arch working set.
// Round-5 anti-spill edits vs r4 (r4: WRITE_SIZE 51MB = scratch spills):
//  (a) pin with "+a" so weights never occupy the 64 arch VGPRs;
//  (b) x-part/u-part MFMAs run BEFORE the h k-loop, so the hoisted L2
//      weight loads are consumed immediately (peak VMEM transients 24->8);
//  (c) sched_group_barrier rhythm caps in-flight ds/vmem fragments;
//  (d) gemm2 recomputes its frame in-branch (no persistent wave-0 regs).
__global__ __launch_bounds__(1024, 4) void encdec_kernel(
    const float* __restrict__ xf, const float* __restrict__ yt, const float* __restrict__ pp,
    const float* __restrict__ ebih, const float* __restrict__ ebhh,
    const float* __restrict__ dbih, const float* __restrict__ dbhh,
    const float* __restrict__ thb0, const float* __restrict__ thb1,
    const float* __restrict__ clb0, const float* __restrict__ clb1,
    const u16* __restrict__ ws, float* __restrict__ outp) {
  __shared__ __align__(16) u16 slab[256 * SSTR];   // r-gate Whh rows (132 KB)
  __shared__ __align__(16) u16 hls[2][16 * HSTR];  // h double buffer (enc+dec)
  __shared__ __align__(16) u16 a1x[16 * HSTR];     // dec: a1; enc: x dbuf [2][16*XSTR]
  __shared__ __align__(16) u16 uls[2][16 * UST2];

  const u16* eWih = ws + W_EWIH;
  const u16* eWhh = ws + W_EWHH;
  const u16* dWih = ws + W_DWIH;
  const u16* dWhh = ws + W_DWHH;
  const u16* thW0 = ws + W_THW0;
  const u16* clW0 = ws + W_CLW0;
  const u16* w1f  = ws + W_W1F;

  const int tid = threadIdx.x;
  const int wave = tid >> 6;        // 16 waves
  const int lane = tid & 63;
  const int col16 = lane & 15;
  const int quad = lane >> 4;
  const int n0 = blockIdx.x * 16;

  const int cidx = wave * 16 + col16;          // owned gate/output column
  const int mz = 256 + cidx, mn = 512 + cidx;

  float hreg[4] = {0.f, 0.f, 0.f, 0.f};

  // Persistent z,n Whh fragments -> AGPR (64 regs, "+a" pinned).
  v4f wz[8], wn[8];
  float bsr, bsz, bin_, bhn;

  const u16* sp = slab + cidx * SSTR + quad * 8;
  // x staging: thread (wave=row, lane=col) covers the 16x64 step slice
  const float* xsrc = xf + ((size_t)(n0 + wave) * LX) * FF + lane;

  // ================= encoder phase =================
  {
    for (int i = tid; i < 256 * 32; i += 1024) {  // stage r-gate Whh slab
      const int row = i >> 5, kb = (i & 31) << 3;
      *reinterpret_cast<v8bf*>(&slab[row * SSTR + kb]) = ld8(eWhh + row * HID + kb);
    }
    for (int i = tid; i < 16 * HSTR; i += 1024) hls[0][i] = 0;
    a1x[wave * XSTR + lane] = f2bf(xsrc[0]);      // stage x(0) into x-buf 0
#pragma unroll
    for (int k = 0; k < 8; ++k) {
      wz[k] = ldw(eWhh + (size_t)mz * HID + k * 32 + quad * 8); pina(wz[k]);
      wn[k] = ldw(eWhh + (size_t)mn * HID + k * 32 + quad * 8); pina(wn[k]);
    }
    bsr = ebih[cidx] + ebhh[cidx];
    bsz = ebih[mz] + ebhh[mz];
    bin_ = ebih[mn];
    bhn = ebhh[mn];

    const u16* pwr = eWih + (size_t)cidx * FF + quad * 8;
    const u16* pwz = eWih + (size_t)mz * FF + quad * 8;
    const u16* pwn = eWih + (size_t)mn * FF + quad * 8;
    __syncthreads();  // slab + h-init + x(0) visible

#pragma unroll 1
    for (int t = 0; t < LX; ++t) {
      float xn = 0.f;
      if (t + 1 < LX) xn = xsrc[(size_t)(t + 1) * FF];  // issue early, use late

      v4f az = {bsz, bsz, bsz, bsz};
      v4f ar = {bsr, bsr, bsr, bsr};
      v4f an = {bhn, bhn, bhn, bhn};
      v4f ai = {bin_, bin_, bin_, bin_};

      __builtin_amdgcn_s_setprio(1);
      // ---- x-part FIRST: L2 weight loads consumed immediately ----
      {
        const u16* xb = a1x + (t & 1) * (16 * XSTR) + col16 * XSTR + quad * 8;
        const v8bf xa0 = ld8(xb);
        const v8bf xa1 = ld8(xb + 32);
        az = mfma16(xa0, ld8(pwz), az);
        az = mfma16(xa1, ld8(pwz + 32), az);
        SGB(0x20, 2); SGB(0x8, 2);
        ar = mfma16(xa0, ld8(pwr), ar);
        ar = mfma16(xa1, ld8(pwr + 32), ar);
        SGB(0x20, 2); SGB(0x8, 2);
        ai = mfma16(xa0, ld8(pwn), ai);
        ai = mfma16(xa1, ld8(pwn + 32), ai);
        SGB(0x20, 2); SGB(0x8, 2);
      }
      // ---- h k-loop: 3 chains, 2 ds_read : 3 mfma rhythm ----
      const u16* hb = hls[t & 1] + col16 * HSTR + quad * 8;
#pragma unroll
      for (int k = 0; k < 8; ++k) {
        const v8bf a = ld8(hb + k * 32);
        az = mfma16(a, asbf(wz[k]), az);
        ar = mfma16(a, ld8(sp + k * 32), ar);
        an = mfma16(a, asbf(wn[k]), an);
        SGB(0x100, 2); SGB(0x8, 3);
      }
      __builtin_amdgcn_s_setprio(0);
#pragma unroll
      for (int r = 0; r < 4; ++r) {
        const float zg = sigm(az[r]);
        const float rg = sigm(ar[r]);
        const float ng = tanh_(ai[r] + rg * an[r]);
        hreg[r] = (1.f - zg) * ng + zg * hreg[r];
        hls[(t + 1) & 1][(quad * 4 + r) * HSTR + cidx] = f2bf(hreg[r]);
      }
      if (t + 1 < LX)
        a1x[((t + 1) & 1) * (16 * XSTR) + wave * XSTR + lane] = f2bf(xn);
      __syncthreads();
    }
  }
  // h_enc = H(168) in hls[0]  (LX even)

  // ================= decoder phase =================
  {
    for (int i = tid; i < 256 * 32; i += 1024) {  // restage slab with dWhh r rows
      const int row = i >> 5, kb = (i & 31) << 3;
      *reinterpret_cast<v8bf*>(&slab[row * SSTR + kb]) = ld8(dWhh + row * HID + kb);
    }
#pragma unroll
    for (int k = 0; k < 8; ++k) {
      wz[k] = ldw(dWhh + (size_t)mz * HID + k * 32 + quad * 8); pina(wz[k]);
      wn[k] = ldw(dWhh + (size_t)mn * HID + k * 32 + quad * 8); pina(wn[k]);
    }
    bsr = dbih[cidx] + dbhh[cidx];
    bsz = dbih[mz] + dbhh[mz];
    bin_ = dbih[mn];
    bhn = dbhh[mn];

    const bool isTh = (wave < 8);
    const int wrow = (wave & 7) * 16 + col16;        // head W0 row
    const u16* pW0 = (isTh ? thW0 : clW0) + (size_t)wrow * HID + quad * 8;
    const float hb0 = isTh ? thb0[wrow] : clb0[wrow];
    const int hcol = (isTh ? 0 : 128) + wrow;        // a1 column this wave writes

    const u16* pur = dWih + (size_t)cidx * 32 + quad * 8;
    const u16* puz = dWih + (size_t)mz * 32 + quad * 8;
    const u16* pun = dWih + (size_t)mn * 32 + quad * 8;

    const int srr = tid >> 5, scc = tid & 31;        // u staging (tid < 512)
    const size_t ybase = (size_t)(n0 + srr) * (LY + 1);
    if (tid < 512) {
      const float v = (scc < FT) ? yt[ybase * FT + scc] : pp[ybase * FOUTC + (scc - FT)];
      uls[0][srr * UST2 + scc] = f2bf(v);
    }

    // GEMM2 for step s (wave 0 only): out(s) = a1(s) @ W1F^T + b1.
    // Entire frame recomputed in-branch: zero persistent wave-0 registers.
    auto gemm2 = [&](int s) {
      const u16* arow = a1x + col16 * HSTR + quad * 8;
      const u16* w1p = w1f + col16 * HID + quad * 8;
      const float b1 = (col16 < 2) ? thb1[col16]
                     : (col16 < FOUTC) ? clb1[col16 - 2] : 0.f;
      v4f acc = {b1, b1, b1, b1};
#pragma unroll
      for (int kt = 0; kt < 8; ++kt) {
        acc = mfma16(ld8(arow + kt * 32), ld8(w1p + kt * 32), acc);
        SGB(0x100, 1); SGB(0x20, 1); SGB(0x8, 1);
      }
      if (col16 < FOUTC) {
#pragma unroll
        for (int r = 0; r < 4; ++r)
          outp[((size_t)(n0 + quad * 4 + r) * LY + s) * FOUTC + col16] = acc[r];
      }
    };

    // GEMM1: a1 = smelu(H @ W0^T + b0); each wave computes its head tile.
    auto gemm1 = [&](const u16* hbase) {
      const u16* hA = hbase + col16 * HSTR + quad * 8;
      v4f acc = {hb0, hb0, hb0, hb0};
#pragma unroll
      for (int k = 0; k < 8; ++k) {
        acc = mfma16(ld8(hA + k * 32), ld8(pW0 + k * 32), acc);
        SGB(0x100, 1); SGB(0x20, 1); SGB(0x8, 1);
      }
#pragma unroll
      for (int r = 0; r < 4; ++r)
        a1x[(quad * 4 + r) * HSTR + hcol] = f2bf(smelu_(acc[r]));
    };

    __syncthreads();  // slab + u_0 visible (last enc h write fenced by enc barrier)

#pragma unroll 1
    for (int t = 0; t < LY; ++t) {
      float un = 0.f;
      if (tid < 512 && t + 1 < LY)
        un = (scc < FT) ? yt[(ybase + t) * FT + scc]
                        : pp[(ybase + t) * FOUTC + (scc - FT)];

      // ---- phase A: gemm2(t-2) reads a1x (written step t-1 phase B) ----
      if (wave == 0 && t >= 2) gemm2(t - 2);

      v4f az = {bsz, bsz, bsz, bsz};
      v4f ar = {bsr, bsr, bsr, bsr};
      v4f an = {bhn, bhn, bhn, bhn};
      v4f ai = {bin_, bin_, bin_, bin_};

      __builtin_amdgcn_s_setprio(1);
      // ---- u-part FIRST (3 L2 loads consumed immediately) ----
      {
        const v8bf ua = ld8(uls[t & 1] + col16 * UST2 + quad * 8);
        az = mfma16(ua, ld8(puz), az);
        ar = mfma16(ua, ld8(pur), ar);
        ai = mfma16(ua, ld8(pun), ai);
        SGB(0x20, 3); SGB(0x8, 3);
      }
      // ---- h k-loop ----
      const u16* hb = hls[t & 1] + col16 * HSTR + quad * 8;
#pragma unroll
      for (int k = 0; k < 8; ++k) {
        const v8bf a = ld8(hb + k * 32);
        az = mfma16(a, asbf(wz[k]), az);
        ar = mfma16(a, ld8(sp + k * 32), ar);
        an = mfma16(a, asbf(wn[k]), an);
        SGB(0x100, 2); SGB(0x8, 3);
      }
      __builtin_amdgcn_s_setprio(0);
#pragma unroll
      for (int r = 0; r < 4; ++r) {
        const float zg = sigm(az[r]);
        const float rg = sigm(ar[r]);
        const float ng = tanh_(ai[r] + rg * an[r]);
        hreg[r] = (1.f - zg) * ng + zg * hreg[r];
        hls[(t + 1) & 1][(quad * 4 + r) * HSTR + cidx] = f2bf(hreg[r]);
      }
      if (tid < 512 && t + 1 < LY) uls[(t + 1) & 1][srr * UST2 + scc] = f2bf(un);
      __syncthreads();  // bar1: gemm2's a1x reads done; H(t+1)/u(t+1) visible

      // ---- phase B: gemm1(t-1) reads hls[t&1] (= H(t)), writes a1x ----
      if (t >= 1) gemm1(hls[t & 1]);
      __syncthreads();  // bar2: a1x(t-1) visible for next step's gemm2
    }

    // ---- epilogue: a1x holds a1(LY-2) ----
    if (wave == 0) gemm2(LY - 2);
    __syncthreads();
    gemm1(hls[LY & 1]);              // a1(LY-1) from H(LY) (= hls[0], LY even)
    __syncthreads();
    if (wave == 0) gemm2(LY - 1);
  }
}

extern "C" void kernel_launch(void* const* d_in, const int* in_sizes, int n_in,
                              void* d_out, int out_size, void* d_ws, size_t ws_size,
                              hipStream_t stream) {
  (void)in_sizes; (void)n_in; (void)ws_size; (void)out_size;
  const float* xf   = (const float*)d_in[0];
  // d_in[1] = x : unused by forward
  const float* yt   = (const float*)d_in[2];
  const float* pp   = (const float*)d_in[3];
  const float* eWih = (const float*)d_in[4];
  const float* eWhh = (const float*)d_in[5];
  const float* ebih = (const float*)d_in[6];
  const float* ebhh = (const float*)d_in[7];
  const float* dWih = (const float*)d_in[8];
  const float* dWhh = (const float*)d_in[9];
  const float* dbih = (const float*)d_in[10];
  const float* dbhh = (const float*)d_in[11];
  const float* thW0 = (const float*)d_in[12];
  const float* thb0 = (const float*)d_in[13];
  const float* thW1 = (const float*)d_in[14];
  const float* thb1 = (const float*)d_in[15];
  const float* clW0 = (const float*)d_in[16];
  const float* clb0 = (const float*)d_in[17];
  const float* clW1 = (const float*)d_in[18];
  const float* clb1 = (const float*)d_in[19];
  float* outp = (float*)d_out;
  u16* ws = (u16*)d_ws;  // needs W_TOTALF*2 ~= 1.05 MB of scratch

  cvt_weights<<<dim3((W_TOTALF + 255) / 256), dim3(256), 0, stream>>>(
      eWih, eWhh, dWih, dWhh, thW0, thW1, clW0, clW1, ws);
  encdec_kernel<<<dim3(128), dim3(1024), 0, stream>>>(
      xf, yt, pp, ebih, ebhh, dbih, dbhh, thb0, thb1, clb0, clb1, ws, outp);
}